// Round 1
// baseline (1055.833 us; speedup 1.0000x reference)
//
#include <hip/hip_runtime.h>

// Problem constants (fixed by the reference file)
#define NN 50000
#define EE 800000
#define HH 128
#define LL 4
#define GG 64

// ---------------------------------------------------------------------------
// CSR build: count in-degree per target, exclusive scan, scatter edges sorted
// by target. Turns the mean-scatter into a per-node gather (no fp atomics in
// the per-layer hot loops).
// ---------------------------------------------------------------------------
__global__ __launch_bounds__(256) void count_kernel(const int* __restrict__ tgt,
                                                    int* __restrict__ cnt, int E) {
  int e = blockIdx.x * 256 + threadIdx.x;
  if (e < E) atomicAdd(&cnt[tgt[e]], 1);
}

__global__ __launch_bounds__(1024) void scan_kernel(const int* __restrict__ cnt,
                                                    int* __restrict__ rp, int n) {
  __shared__ int part[1024];
  int tid = threadIdx.x;
  int chunk = (n + 1023) >> 10;
  int s = tid * chunk;
  int e = min(s + chunk, n);
  int sum = 0;
  for (int i = s; i < e; ++i) sum += cnt[i];
  part[tid] = sum;
  __syncthreads();
  // Hillis-Steele inclusive scan over the 1024 partials
  for (int off = 1; off < 1024; off <<= 1) {
    int v = (tid >= off) ? part[tid - off] : 0;
    __syncthreads();
    part[tid] += v;
    __syncthreads();
  }
  int base = (tid > 0) ? part[tid - 1] : 0;
  for (int i = s; i < e; ++i) { rp[i] = base; base += cnt[i]; }
  if (tid == 1023) rp[n] = part[1023];
}

__global__ __launch_bounds__(256) void scatter_kernel(const int* __restrict__ src,
                                                      const int* __restrict__ tgt,
                                                      const float* __restrict__ attr,
                                                      const int* __restrict__ rp,
                                                      int* __restrict__ cur,
                                                      int* __restrict__ src_s,
                                                      float* __restrict__ attr_s, int E) {
  int e = blockIdx.x * 256 + threadIdx.x;
  if (e < E) {
    int t = tgt[e];
    int p = rp[t] + atomicAdd(&cur[t], 1);
    src_s[p] = src[e];
    attr_s[p] = attr[e];
  }
}

__global__ __launch_bounds__(256) void vn_init_kernel(const float* __restrict__ emb,
                                                      float* __restrict__ vn, int total) {
  int i = blockIdx.x * 256 + threadIdx.x;
  if (i < total) vn[i] = emb[i & (HH - 1)];
}

// hvn[n] = h_prev[n] + vn[batch[n]]  (compact pitch-128 buffer so the edge
// gather reads a dense array regardless of which layer h_prev lives in)
__global__ __launch_bounds__(256) void add_vn_kernel(const float4* __restrict__ hp, int pitch4,
                                                     const float4* __restrict__ vn,
                                                     const int* __restrict__ batch,
                                                     float4* __restrict__ hvn, int N) {
  int idx = blockIdx.x * 256 + threadIdx.x;
  if (idx >= N * (HH / 4)) return;
  int n = idx >> 5;           // HH/4 == 32
  int c4 = idx & 31;
  int g = batch[n];
  float4 a = hp[(size_t)n * pitch4 + c4];
  float4 b = vn[g * 32 + c4];
  float4 r;
  r.x = a.x + b.x; r.y = a.y + b.y; r.z = a.z + b.z; r.w = a.w + b.w;
  hvn[idx] = r;
}

// z[n] = (1+eps)*hvn[n] + (1/deg) * sum_{e->n} relu(hvn[src_e] + attr_e*eW + eb)
// One block (128 threads = 2 waves) per node; lane = column; coalesced 512B
// row gathers; accumulate in registers.
__global__ __launch_bounds__(128) void agg_kernel(const float* __restrict__ hvn,
                                                  const int* __restrict__ rp,
                                                  const int* __restrict__ src_s,
                                                  const float* __restrict__ attr_s,
                                                  const float* __restrict__ eW,
                                                  const float* __restrict__ eb,
                                                  const float* __restrict__ epsp,
                                                  float* __restrict__ z, int N) {
  int n = blockIdx.x;
  int c = threadIdx.x;
  float ew = eW[c];
  float ebv = eb[c];
  int rs = rp[n], re = rp[n + 1];
  float acc = 0.f;
  for (int k = rs; k < re; ++k) {
    int s = src_s[k];
    float a = attr_s[k];
    float v = hvn[(size_t)s * HH + c] + a * ew + ebv;
    acc += fmaxf(v, 0.f);
  }
  float hs = hvn[(size_t)n * HH + c];
  float deg = fmaxf((float)(re - rs), 1.f);
  float eps = epsp[0];
  z[(size_t)n * HH + c] = (1.f + eps) * hs + acc / deg;
}

// h_new = relu(z @ W1 + b1) @ W2 + b2, written to out[:, layer*128:+128].
// 64-row tile in LDS (32 KB, reused for the relu intermediate); each thread
// owns an 8x4 register block; weights streamed from L1/L2.
__global__ __launch_bounds__(256) void mlp_kernel(const float* __restrict__ z,
                                                  const float* __restrict__ W1,
                                                  const float* __restrict__ b1,
                                                  const float* __restrict__ W2,
                                                  const float* __restrict__ b2,
                                                  float* __restrict__ out, int layer, int N) {
  __shared__ float zs[64 * 128];
  int tid = threadIdx.x;
  int row0 = blockIdx.x * 64;
  const float4* z4 = (const float4*)z;
  float4* zs4 = (float4*)zs;
#pragma unroll
  for (int it = 0; it < 8; ++it) {
    int f = tid + it * 256;         // [0, 2048)
    int r = f >> 5, k4 = f & 31;
    int n = row0 + r;
    float4 v = make_float4(0.f, 0.f, 0.f, 0.f);
    if (n < N) v = z4[(size_t)n * 32 + k4];
    zs4[f] = v;
  }
  __syncthreads();
  int lj = tid & 31;                // float4-column owned by this thread
  int r0 = (tid >> 5) * 8;          // first of 8 rows owned by this thread
  float acc[8][4];
#pragma unroll
  for (int rr = 0; rr < 8; ++rr)
#pragma unroll
    for (int q = 0; q < 4; ++q) acc[rr][q] = 0.f;

  const float4* W14 = (const float4*)W1;
  for (int k = 0; k < 128; ++k) {
    float4 w = W14[k * 32 + lj];
#pragma unroll
    for (int rr = 0; rr < 8; ++rr) {
      float zv = zs[(r0 + rr) * 128 + k];
      acc[rr][0] = fmaf(zv, w.x, acc[rr][0]);
      acc[rr][1] = fmaf(zv, w.y, acc[rr][1]);
      acc[rr][2] = fmaf(zv, w.z, acc[rr][2]);
      acc[rr][3] = fmaf(zv, w.w, acc[rr][3]);
    }
  }
  float4 bb = ((const float4*)b1)[lj];
  __syncthreads();  // all stage-1 reads of zs complete before overwrite
#pragma unroll
  for (int rr = 0; rr < 8; ++rr) {
    float4 t;
    t.x = fmaxf(acc[rr][0] + bb.x, 0.f);
    t.y = fmaxf(acc[rr][1] + bb.y, 0.f);
    t.z = fmaxf(acc[rr][2] + bb.z, 0.f);
    t.w = fmaxf(acc[rr][3] + bb.w, 0.f);
    zs4[(r0 + rr) * 32 + lj] = t;
  }
  __syncthreads();
#pragma unroll
  for (int rr = 0; rr < 8; ++rr)
#pragma unroll
    for (int q = 0; q < 4; ++q) acc[rr][q] = 0.f;
  const float4* W24 = (const float4*)W2;
  for (int k = 0; k < 128; ++k) {
    float4 w = W24[k * 32 + lj];
#pragma unroll
    for (int rr = 0; rr < 8; ++rr) {
      float tv = zs[(r0 + rr) * 128 + k];
      acc[rr][0] = fmaf(tv, w.x, acc[rr][0]);
      acc[rr][1] = fmaf(tv, w.y, acc[rr][1]);
      acc[rr][2] = fmaf(tv, w.z, acc[rr][2]);
      acc[rr][3] = fmaf(tv, w.w, acc[rr][3]);
    }
  }
  float4 b2v = ((const float4*)b2)[lj];
  float4* out4 = (float4*)out;
#pragma unroll
  for (int rr = 0; rr < 8; ++rr) {
    int n = row0 + r0 + rr;
    if (n < N) {
      float4 o;
      o.x = acc[rr][0] + b2v.x;
      o.y = acc[rr][1] + b2v.y;
      o.z = acc[rr][2] + b2v.z;
      o.w = acc[rr][3] + b2v.w;
      out4[(size_t)n * (LL * HH / 4) + layer * (HH / 4) + lj] = o;
    }
  }
}

// vt[g] = sum over nodes of graph g of out[:, layer slice] + vn[g]
// batch = (n*G)//N (sorted), so graph g covers [ceil(gN/G), ceil((g+1)N/G))
__global__ __launch_bounds__(256) void graph_sum_kernel(const float* __restrict__ outbase,
                                                        const float* __restrict__ vn,
                                                        float* __restrict__ vt, int N, int G) {
  int g = blockIdx.x;
  int start = (int)(((long long)g * N + G - 1) / G);
  int end = (int)(((long long)(g + 1) * N + G - 1) / G);
  int c4 = threadIdx.x & 31;
  int rl = threadIdx.x >> 5;      // 8 row-lanes
  const float4* ob = (const float4*)outbase;  // pitch = LL*HH/4 = 128 float4
  float4 acc = make_float4(0.f, 0.f, 0.f, 0.f);
  for (int n = start + rl; n < end; n += 8) {
    float4 v = ob[(size_t)n * (LL * HH / 4) + c4];
    acc.x += v.x; acc.y += v.y; acc.z += v.z; acc.w += v.w;
  }
  __shared__ float4 sm[256];
  sm[threadIdx.x] = acc;
  __syncthreads();
  for (int s = 4; s >= 1; s >>= 1) {
    if (rl < s) {
      float4 o = sm[(rl + s) * 32 + c4];
      float4 m = sm[rl * 32 + c4];
      m.x += o.x; m.y += o.y; m.z += o.z; m.w += o.w;
      sm[rl * 32 + c4] = m;
    }
    __syncthreads();
  }
  if (rl == 0) {
    float4 v = ((const float4*)vn)[g * 32 + c4];
    float4 m = sm[c4];
    m.x += v.x; m.y += v.y; m.z += v.z; m.w += v.w;
    ((float4*)vt)[g * 32 + c4] = m;
  }
}

// vn = relu(relu(vt @ W1 + b1) @ W2 + b2) — tiny (64 rows), one block/graph
__global__ __launch_bounds__(128) void vn_mlp_kernel(const float* __restrict__ vt,
                                                     const float* __restrict__ W1,
                                                     const float* __restrict__ b1,
                                                     const float* __restrict__ W2,
                                                     const float* __restrict__ b2,
                                                     float* __restrict__ vn, int G) {
  int g = blockIdx.x, j = threadIdx.x;
  __shared__ float vr[128];
  __shared__ float tr[128];
  vr[j] = vt[g * HH + j];
  __syncthreads();
  float a = b1[j];
  for (int k = 0; k < 128; ++k) a = fmaf(vr[k], W1[k * HH + j], a);
  tr[j] = fmaxf(a, 0.f);
  __syncthreads();
  float o = b2[j];
  for (int k = 0; k < 128; ++k) o = fmaf(tr[k], W2[k * HH + j], o);
  vn[g * HH + j] = fmaxf(o, 0.f);
}

extern "C" void kernel_launch(void* const* d_in, const int* in_sizes, int n_in,
                              void* d_out, int out_size, void* d_ws, size_t ws_size,
                              hipStream_t stream) {
  const int N = NN, E = EE, H = HH, L = LL, G = GG;
  const float* x         = (const float*)d_in[0];
  const float* edge_attr = (const float*)d_in[1];
  const float* conv_W1   = (const float*)d_in[2];
  const float* conv_b1   = (const float*)d_in[3];
  const float* conv_W2   = (const float*)d_in[4];
  const float* conv_b2   = (const float*)d_in[5];
  const float* conv_eps  = (const float*)d_in[6];
  const float* edge_W    = (const float*)d_in[7];
  const float* edge_b    = (const float*)d_in[8];
  const float* vn_W1     = (const float*)d_in[9];
  const float* vn_b1     = (const float*)d_in[10];
  const float* vn_W2     = (const float*)d_in[11];
  const float* vn_b2     = (const float*)d_in[12];
  const float* vn_emb    = (const float*)d_in[13];
  const int*   edge_index= (const int*)d_in[14];
  const int*   batch     = (const int*)d_in[15];
  float* out = (float*)d_out;

  // workspace carve-up (~58.4 MB total)
  char* ws = (char*)d_ws;
  size_t off = 0;
  auto take = [&](size_t bytes) -> void* {
    void* p = ws + off;
    off = (off + bytes + 255) & ~(size_t)255;
    return p;
  };
  int*   cnt    = (int*)take((size_t)N * 4);        // counts, reused as cursor
  int*   rp     = (int*)take((size_t)(N + 1) * 4);  // CSR row_ptr
  int*   src_s  = (int*)take((size_t)E * 4);        // src sorted by tgt
  float* attr_s = (float*)take((size_t)E * 4);      // attr sorted by tgt
  float* hvn    = (float*)take((size_t)N * H * 4);  // h + vn[batch]
  float* zbuf   = (float*)take((size_t)N * H * 4);  // GIN pre-MLP activation
  float* vn     = (float*)take((size_t)G * H * 4);
  float* vt     = (float*)take((size_t)G * H * 4);

  const int* src = edge_index;
  const int* tgt = edge_index + E;

  // CSR build (inputs are restored before every call, so rebuild every call)
  hipMemsetAsync(cnt, 0, (size_t)N * 4, stream);
  count_kernel<<<(E + 255) / 256, 256, 0, stream>>>(tgt, cnt, E);
  scan_kernel<<<1, 1024, 0, stream>>>(cnt, rp, N);
  hipMemsetAsync(cnt, 0, (size_t)N * 4, stream);
  scatter_kernel<<<(E + 255) / 256, 256, 0, stream>>>(src, tgt, edge_attr, rp, cnt,
                                                      src_s, attr_s, E);
  vn_init_kernel<<<(G * H + 255) / 256, 256, 0, stream>>>(vn_emb, vn, G * H);

  for (int i = 0; i < L; ++i) {
    const float4* hp;
    int pitch4;
    if (i == 0) { hp = (const float4*)x; pitch4 = H / 4; }
    else        { hp = (const float4*)out + (size_t)(i - 1) * (H / 4); pitch4 = L * H / 4; }
    add_vn_kernel<<<(N * (H / 4) + 255) / 256, 256, 0, stream>>>(
        hp, pitch4, (const float4*)vn, batch, (float4*)hvn, N);
    agg_kernel<<<N, 128, 0, stream>>>(hvn, rp, src_s, attr_s,
                                      edge_W + (size_t)i * H, edge_b + (size_t)i * H,
                                      conv_eps + i, zbuf, N);
    mlp_kernel<<<(N + 63) / 64, 256, 0, stream>>>(
        zbuf, conv_W1 + (size_t)i * H * H, conv_b1 + (size_t)i * H,
        conv_W2 + (size_t)i * H * H, conv_b2 + (size_t)i * H, out, i, N);
    if (i < L - 1) {
      graph_sum_kernel<<<G, 256, 0, stream>>>(out + (size_t)i * H, vn, vt, N, G);
      vn_mlp_kernel<<<G, 128, 0, stream>>>(vt, vn_W1 + (size_t)i * H * H,
                                           vn_b1 + (size_t)i * H,
                                           vn_W2 + (size_t)i * H * H,
                                           vn_b2 + (size_t)i * H, vn, G);
    }
  }
}

// Round 2
// 774.666 us; speedup vs baseline: 1.3630x; 1.3630x over previous
//
#include <hip/hip_runtime.h>

// Problem constants (fixed by the reference file)
#define NN 50000
#define EE 800000
#define HH 128
#define LL 4
#define GG 64

// ---------------------------------------------------------------------------
// bf16 pack helpers (RTNE)
// ---------------------------------------------------------------------------
__device__ __forceinline__ unsigned bf_round(float f) {
  unsigned u = __float_as_uint(f);
  return (u + 0x7fffu + ((u >> 16) & 1u)) >> 16;
}
__device__ __forceinline__ unsigned bf_pack2(float lo, float hi) {
  return bf_round(lo) | (bf_round(hi) << 16);
}

// ---------------------------------------------------------------------------
// CSR build: count in-degree, 3-phase parallel exclusive scan, scatter edges
// sorted by target as int2{src, attr_bits}.
// ---------------------------------------------------------------------------
__global__ __launch_bounds__(256) void count_kernel(const int* __restrict__ tgt,
                                                    int* __restrict__ cnt, int E) {
  int e = blockIdx.x * 256 + threadIdx.x;
  if (e < E) atomicAdd(&cnt[tgt[e]], 1);
}

__global__ __launch_bounds__(256) void blocksum_kernel(const int* __restrict__ cnt,
                                                       int* __restrict__ bs, int N) {
  int i = blockIdx.x * 256 + threadIdx.x;
  int v = (i < N) ? cnt[i] : 0;
  __shared__ int sm[256];
  sm[threadIdx.x] = v;
  __syncthreads();
  for (int s = 128; s >= 1; s >>= 1) {
    if (threadIdx.x < s) sm[threadIdx.x] += sm[threadIdx.x + s];
    __syncthreads();
  }
  if (threadIdx.x == 0) bs[blockIdx.x] = sm[0];
}

// single block: exclusive scan of bs[0..nb) in place; bs[nb] = total (nb<=256)
__global__ __launch_bounds__(256) void bs_scan_kernel(int* __restrict__ bs, int nb) {
  __shared__ int sm[256];
  int t = threadIdx.x;
  int v = (t < nb) ? bs[t] : 0;
  sm[t] = v;
  __syncthreads();
  for (int off = 1; off < 256; off <<= 1) {
    int u = (t >= off) ? sm[t - off] : 0;
    __syncthreads();
    sm[t] += u;
    __syncthreads();
  }
  if (t < nb) bs[t] = sm[t] - v;
  if (t == 255) bs[nb] = sm[255];
}

__global__ __launch_bounds__(256) void blockscan_kernel(const int* __restrict__ cnt,
                                                        const int* __restrict__ bs,
                                                        int* __restrict__ rp, int N, int nb) {
  int b = blockIdx.x, t = threadIdx.x;
  int i = b * 256 + t;
  int v = (i < N) ? cnt[i] : 0;
  __shared__ int sm[256];
  sm[t] = v;
  __syncthreads();
  for (int off = 1; off < 256; off <<= 1) {
    int u = (t >= off) ? sm[t - off] : 0;
    __syncthreads();
    sm[t] += u;
    __syncthreads();
  }
  if (i < N) rp[i] = sm[t] - v + bs[b];
  if (b == 0 && t == 0) rp[N] = bs[nb];
}

__global__ __launch_bounds__(256) void scatter_kernel(const int* __restrict__ src,
                                                      const int* __restrict__ tgt,
                                                      const float* __restrict__ attr,
                                                      const int* __restrict__ rp,
                                                      int* __restrict__ cur,
                                                      int2* __restrict__ es, int E) {
  int e = blockIdx.x * 256 + threadIdx.x;
  if (e < E) {
    int t = tgt[e];
    int p = rp[t] + atomicAdd(&cur[t], 1);
    int2 rec;
    rec.x = src[e];
    rec.y = __float_as_int(attr[e]);
    es[p] = rec;
  }
}

__global__ __launch_bounds__(256) void vn_init_kernel(const float* __restrict__ emb,
                                                      float* __restrict__ vn, int total) {
  int i = blockIdx.x * 256 + threadIdx.x;
  if (i < total) vn[i] = emb[i & (HH - 1)];
}

// hbf[n] = bf16(h_prev[n] + vn[batch[n]]), packed 2 cols per uint (row = 256 B)
__global__ __launch_bounds__(256) void pack_kernel(const float4* __restrict__ hp, int pitch4,
                                                   const float4* __restrict__ vn,
                                                   const int* __restrict__ batch,
                                                   uint2* __restrict__ hbf, int N) {
  int idx = blockIdx.x * 256 + threadIdx.x;
  if (idx >= N * (HH / 4)) return;
  int n = idx >> 5;  // HH/4 == 32
  int c4 = idx & 31;
  int g = batch[n];
  float4 a = hp[(size_t)n * pitch4 + c4];
  float4 b = vn[g * 32 + c4];
  uint2 o;
  o.x = bf_pack2(a.x + b.x, a.y + b.y);
  o.y = bf_pack2(a.z + b.z, a.w + b.w);
  hbf[idx] = o;
}

// z[n] = (1+eps)*(h[n]+vn[g]) + (1/deg) * sum_e relu(hbf[src_e] + attr_e*eW + eb)
// One wave per node (2 nodes / 128-thread block); lane owns columns
// {2*lane, 2*lane+1} as a packed bf16x2; edge loop unrolled 4x for MLP
// (memory-level parallelism): 4 independent 256 B coalesced gathers in flight.
__global__ __launch_bounds__(128) void agg_kernel(const unsigned* __restrict__ hbf,
                                                  const float2* __restrict__ hp2, int pitch2,
                                                  const float2* __restrict__ vn2,
                                                  const int* __restrict__ batch,
                                                  const int2* __restrict__ es,
                                                  const int* __restrict__ rp,
                                                  const float2* __restrict__ eW2,
                                                  const float2* __restrict__ eb2,
                                                  const float* __restrict__ epsp,
                                                  float2* __restrict__ z2, int N) {
  int wave = threadIdx.x >> 6;
  int lane = threadIdx.x & 63;
  int n = blockIdx.x * 2 + wave;
  if (n >= N) return;
  float2 ew = eW2[lane];
  float2 eb = eb2[lane];
  int rs = rp[n], re = rp[n + 1];
  float acc0 = 0.f, acc1 = 0.f;
  int k = rs;
  for (; k + 4 <= re; k += 4) {
    int2 e0 = es[k + 0];
    int2 e1 = es[k + 1];
    int2 e2 = es[k + 2];
    int2 e3 = es[k + 3];
    unsigned p0 = hbf[((unsigned)e0.x << 6) + lane];
    unsigned p1 = hbf[((unsigned)e1.x << 6) + lane];
    unsigned p2 = hbf[((unsigned)e2.x << 6) + lane];
    unsigned p3 = hbf[((unsigned)e3.x << 6) + lane];
    float a0 = __int_as_float(e0.y), a1 = __int_as_float(e1.y);
    float a2 = __int_as_float(e2.y), a3 = __int_as_float(e3.y);
    acc0 += fmaxf(__uint_as_float(p0 << 16) + fmaf(a0, ew.x, eb.x), 0.f);
    acc1 += fmaxf(__uint_as_float(p0 & 0xffff0000u) + fmaf(a0, ew.y, eb.y), 0.f);
    acc0 += fmaxf(__uint_as_float(p1 << 16) + fmaf(a1, ew.x, eb.x), 0.f);
    acc1 += fmaxf(__uint_as_float(p1 & 0xffff0000u) + fmaf(a1, ew.y, eb.y), 0.f);
    acc0 += fmaxf(__uint_as_float(p2 << 16) + fmaf(a2, ew.x, eb.x), 0.f);
    acc1 += fmaxf(__uint_as_float(p2 & 0xffff0000u) + fmaf(a2, ew.y, eb.y), 0.f);
    acc0 += fmaxf(__uint_as_float(p3 << 16) + fmaf(a3, ew.x, eb.x), 0.f);
    acc1 += fmaxf(__uint_as_float(p3 & 0xffff0000u) + fmaf(a3, ew.y, eb.y), 0.f);
  }
  for (; k < re; ++k) {
    int2 e = es[k];
    unsigned p = hbf[((unsigned)e.x << 6) + lane];
    float a = __int_as_float(e.y);
    acc0 += fmaxf(__uint_as_float(p << 16) + fmaf(a, ew.x, eb.x), 0.f);
    acc1 += fmaxf(__uint_as_float(p & 0xffff0000u) + fmaf(a, ew.y, eb.y), 0.f);
  }
  int g = batch[n];
  float2 h = hp2[(size_t)n * pitch2 + lane];
  float2 v = vn2[(size_t)g * 64 + lane];
  float hs0 = h.x + v.x;
  float hs1 = h.y + v.y;
  float inv = 1.f / fmaxf((float)(re - rs), 1.f);
  float onep = 1.f + epsp[0];
  float2 o;
  o.x = fmaf(onep, hs0, acc0 * inv);
  o.y = fmaf(onep, hs1, acc1 * inv);
  z2[(size_t)n * 64 + lane] = o;
}

// h_new = relu(z @ W1 + b1) @ W2 + b2 -> out[:, layer*128:+128].
// 64-row tile in LDS (reused for the relu intermediate); 8x4 register block
// per thread; k-loop chunked by 4 so LDS reads are ds_read_b128.
__global__ __launch_bounds__(256) void mlp_kernel(const float* __restrict__ z,
                                                  const float* __restrict__ W1,
                                                  const float* __restrict__ b1,
                                                  const float* __restrict__ W2,
                                                  const float* __restrict__ b2,
                                                  float* __restrict__ out, int layer, int N) {
  __shared__ float zs[64 * 128];
  int tid = threadIdx.x;
  int row0 = blockIdx.x * 64;
  const float4* z4 = (const float4*)z;
  float4* zs4 = (float4*)zs;
#pragma unroll
  for (int it = 0; it < 8; ++it) {
    int f = tid + it * 256;  // [0, 2048)
    int r = f >> 5, k4 = f & 31;
    int n = row0 + r;
    float4 v = make_float4(0.f, 0.f, 0.f, 0.f);
    if (n < N) v = z4[(size_t)n * 32 + k4];
    zs4[f] = v;
  }
  __syncthreads();
  int lj = tid & 31;        // float4-column owned by this thread
  int r0 = (tid >> 5) * 8;  // first of 8 rows owned by this thread
  float acc[8][4];
#pragma unroll
  for (int rr = 0; rr < 8; ++rr)
#pragma unroll
    for (int q = 0; q < 4; ++q) acc[rr][q] = 0.f;

  const float4* W14 = (const float4*)W1;
  for (int kc = 0; kc < 32; ++kc) {
    float4 w0 = W14[(kc * 4 + 0) * 32 + lj];
    float4 w1 = W14[(kc * 4 + 1) * 32 + lj];
    float4 w2 = W14[(kc * 4 + 2) * 32 + lj];
    float4 w3 = W14[(kc * 4 + 3) * 32 + lj];
#pragma unroll
    for (int rr = 0; rr < 8; ++rr) {
      float4 zv = zs4[(r0 + rr) * 32 + kc];
      acc[rr][0] = fmaf(zv.x, w0.x, acc[rr][0]);
      acc[rr][1] = fmaf(zv.x, w0.y, acc[rr][1]);
      acc[rr][2] = fmaf(zv.x, w0.z, acc[rr][2]);
      acc[rr][3] = fmaf(zv.x, w0.w, acc[rr][3]);
      acc[rr][0] = fmaf(zv.y, w1.x, acc[rr][0]);
      acc[rr][1] = fmaf(zv.y, w1.y, acc[rr][1]);
      acc[rr][2] = fmaf(zv.y, w1.z, acc[rr][2]);
      acc[rr][3] = fmaf(zv.y, w1.w, acc[rr][3]);
      acc[rr][0] = fmaf(zv.z, w2.x, acc[rr][0]);
      acc[rr][1] = fmaf(zv.z, w2.y, acc[rr][1]);
      acc[rr][2] = fmaf(zv.z, w2.z, acc[rr][2]);
      acc[rr][3] = fmaf(zv.z, w2.w, acc[rr][3]);
      acc[rr][0] = fmaf(zv.w, w3.x, acc[rr][0]);
      acc[rr][1] = fmaf(zv.w, w3.y, acc[rr][1]);
      acc[rr][2] = fmaf(zv.w, w3.z, acc[rr][2]);
      acc[rr][3] = fmaf(zv.w, w3.w, acc[rr][3]);
    }
  }
  float4 bb = ((const float4*)b1)[lj];
  __syncthreads();  // stage-1 reads complete before overwrite
#pragma unroll
  for (int rr = 0; rr < 8; ++rr) {
    float4 t;
    t.x = fmaxf(acc[rr][0] + bb.x, 0.f);
    t.y = fmaxf(acc[rr][1] + bb.y, 0.f);
    t.z = fmaxf(acc[rr][2] + bb.z, 0.f);
    t.w = fmaxf(acc[rr][3] + bb.w, 0.f);
    zs4[(r0 + rr) * 32 + lj] = t;
  }
  __syncthreads();
#pragma unroll
  for (int rr = 0; rr < 8; ++rr)
#pragma unroll
    for (int q = 0; q < 4; ++q) acc[rr][q] = 0.f;
  const float4* W24 = (const float4*)W2;
  for (int kc = 0; kc < 32; ++kc) {
    float4 w0 = W24[(kc * 4 + 0) * 32 + lj];
    float4 w1 = W24[(kc * 4 + 1) * 32 + lj];
    float4 w2 = W24[(kc * 4 + 2) * 32 + lj];
    float4 w3 = W24[(kc * 4 + 3) * 32 + lj];
#pragma unroll
    for (int rr = 0; rr < 8; ++rr) {
      float4 zv = zs4[(r0 + rr) * 32 + kc];
      acc[rr][0] = fmaf(zv.x, w0.x, acc[rr][0]);
      acc[rr][1] = fmaf(zv.x, w0.y, acc[rr][1]);
      acc[rr][2] = fmaf(zv.x, w0.z, acc[rr][2]);
      acc[rr][3] = fmaf(zv.x, w0.w, acc[rr][3]);
      acc[rr][0] = fmaf(zv.y, w1.x, acc[rr][0]);
      acc[rr][1] = fmaf(zv.y, w1.y, acc[rr][1]);
      acc[rr][2] = fmaf(zv.y, w1.z, acc[rr][2]);
      acc[rr][3] = fmaf(zv.y, w1.w, acc[rr][3]);
      acc[rr][0] = fmaf(zv.z, w2.x, acc[rr][0]);
      acc[rr][1] = fmaf(zv.z, w2.y, acc[rr][1]);
      acc[rr][2] = fmaf(zv.z, w2.z, acc[rr][2]);
      acc[rr][3] = fmaf(zv.z, w2.w, acc[rr][3]);
      acc[rr][0] = fmaf(zv.w, w3.x, acc[rr][0]);
      acc[rr][1] = fmaf(zv.w, w3.y, acc[rr][1]);
      acc[rr][2] = fmaf(zv.w, w3.z, acc[rr][2]);
      acc[rr][3] = fmaf(zv.w, w3.w, acc[rr][3]);
    }
  }
  float4 b2v = ((const float4*)b2)[lj];
  float4* out4 = (float4*)out;
#pragma unroll
  for (int rr = 0; rr < 8; ++rr) {
    int n = row0 + r0 + rr;
    if (n < N) {
      float4 o;
      o.x = acc[rr][0] + b2v.x;
      o.y = acc[rr][1] + b2v.y;
      o.z = acc[rr][2] + b2v.z;
      o.w = acc[rr][3] + b2v.w;
      out4[(size_t)n * (LL * HH / 4) + layer * (HH / 4) + lj] = o;
    }
  }
}

// vt[g] = sum over nodes of graph g of out[:, layer slice] + vn[g]
__global__ __launch_bounds__(256) void graph_sum_kernel(const float* __restrict__ outbase,
                                                        const float* __restrict__ vn,
                                                        float* __restrict__ vt, int N, int G) {
  int g = blockIdx.x;
  int start = (int)(((long long)g * N + G - 1) / G);
  int end = (int)(((long long)(g + 1) * N + G - 1) / G);
  int c4 = threadIdx.x & 31;
  int rl = threadIdx.x >> 5;
  const float4* ob = (const float4*)outbase;  // pitch = LL*HH/4
  float4 acc = make_float4(0.f, 0.f, 0.f, 0.f);
  for (int n = start + rl; n < end; n += 8) {
    float4 v = ob[(size_t)n * (LL * HH / 4) + c4];
    acc.x += v.x; acc.y += v.y; acc.z += v.z; acc.w += v.w;
  }
  __shared__ float4 sm[256];
  sm[threadIdx.x] = acc;
  __syncthreads();
  for (int s = 4; s >= 1; s >>= 1) {
    if (rl < s) {
      float4 o = sm[(rl + s) * 32 + c4];
      float4 m = sm[rl * 32 + c4];
      m.x += o.x; m.y += o.y; m.z += o.z; m.w += o.w;
      sm[rl * 32 + c4] = m;
    }
    __syncthreads();
  }
  if (rl == 0) {
    float4 v = ((const float4*)vn)[g * 32 + c4];
    float4 m = sm[c4];
    m.x += v.x; m.y += v.y; m.z += v.z; m.w += v.w;
    ((float4*)vt)[g * 32 + c4] = m;
  }
}

// vn = relu(relu(vt @ W1 + b1) @ W2 + b2) — tiny, one block/graph
__global__ __launch_bounds__(128) void vn_mlp_kernel(const float* __restrict__ vt,
                                                     const float* __restrict__ W1,
                                                     const float* __restrict__ b1,
                                                     const float* __restrict__ W2,
                                                     const float* __restrict__ b2,
                                                     float* __restrict__ vn, int G) {
  int g = blockIdx.x, j = threadIdx.x;
  __shared__ float vr[128];
  __shared__ float tr[128];
  vr[j] = vt[g * HH + j];
  __syncthreads();
  float a = b1[j];
  for (int k = 0; k < 128; ++k) a = fmaf(vr[k], W1[k * HH + j], a);
  tr[j] = fmaxf(a, 0.f);
  __syncthreads();
  float o = b2[j];
  for (int k = 0; k < 128; ++k) o = fmaf(tr[k], W2[k * HH + j], o);
  vn[g * HH + j] = fmaxf(o, 0.f);
}

extern "C" void kernel_launch(void* const* d_in, const int* in_sizes, int n_in,
                              void* d_out, int out_size, void* d_ws, size_t ws_size,
                              hipStream_t stream) {
  const int N = NN, E = EE, H = HH, L = LL, G = GG;
  const float* x          = (const float*)d_in[0];
  const float* edge_attr  = (const float*)d_in[1];
  const float* conv_W1    = (const float*)d_in[2];
  const float* conv_b1    = (const float*)d_in[3];
  const float* conv_W2    = (const float*)d_in[4];
  const float* conv_b2    = (const float*)d_in[5];
  const float* conv_eps   = (const float*)d_in[6];
  const float* edge_W     = (const float*)d_in[7];
  const float* edge_b     = (const float*)d_in[8];
  const float* vn_W1      = (const float*)d_in[9];
  const float* vn_b1      = (const float*)d_in[10];
  const float* vn_W2      = (const float*)d_in[11];
  const float* vn_b2      = (const float*)d_in[12];
  const float* vn_emb     = (const float*)d_in[13];
  const int*   edge_index = (const int*)d_in[14];
  const int*   batch      = (const int*)d_in[15];
  float* out = (float*)d_out;

  const int nb = (N + 255) / 256;  // scan blocks

  // workspace carve-up
  char* ws = (char*)d_ws;
  size_t off = 0;
  auto take = [&](size_t bytes) -> void* {
    void* p = ws + off;
    off = (off + bytes + 255) & ~(size_t)255;
    return p;
  };
  int*      cnt  = (int*)take((size_t)N * 4);            // counts / cursor
  int*      rp   = (int*)take((size_t)(N + 1) * 4);      // CSR row_ptr
  int*      bs   = (int*)take((size_t)(nb + 1) * 4);     // block sums
  int2*     es   = (int2*)take((size_t)E * 8);           // {src, attr} by tgt
  unsigned* hbf  = (unsigned*)take((size_t)N * (H / 2) * 4);  // bf16 h+vn
  float*    zbuf = (float*)take((size_t)N * H * 4);      // GIN pre-MLP act
  float*    vn   = (float*)take((size_t)G * H * 4);
  float*    vt   = (float*)take((size_t)G * H * 4);

  const int* src = edge_index;
  const int* tgt = edge_index + E;

  // CSR build (rebuilt every call; ws is re-poisoned before each launch)
  hipMemsetAsync(cnt, 0, (size_t)N * 4, stream);
  count_kernel<<<(E + 255) / 256, 256, 0, stream>>>(tgt, cnt, E);
  blocksum_kernel<<<nb, 256, 0, stream>>>(cnt, bs, N);
  bs_scan_kernel<<<1, 256, 0, stream>>>(bs, nb);
  blockscan_kernel<<<nb, 256, 0, stream>>>(cnt, bs, rp, N, nb);
  hipMemsetAsync(cnt, 0, (size_t)N * 4, stream);
  scatter_kernel<<<(E + 255) / 256, 256, 0, stream>>>(src, tgt, edge_attr, rp, cnt, es, E);
  vn_init_kernel<<<(G * H + 255) / 256, 256, 0, stream>>>(vn_emb, vn, G * H);

  for (int i = 0; i < L; ++i) {
    const float* hp;
    int pitch;
    if (i == 0) { hp = x; pitch = H; }
    else        { hp = out + (size_t)(i - 1) * H; pitch = L * H; }
    pack_kernel<<<(N * (H / 4) + 255) / 256, 256, 0, stream>>>(
        (const float4*)hp, pitch / 4, (const float4*)vn, batch, (uint2*)hbf, N);
    agg_kernel<<<(N + 1) / 2, 128, 0, stream>>>(
        hbf, (const float2*)hp, pitch / 2, (const float2*)vn, batch, es, rp,
        (const float2*)(edge_W + (size_t)i * H), (const float2*)(edge_b + (size_t)i * H),
        conv_eps + i, (float2*)zbuf, N);
    mlp_kernel<<<(N + 63) / 64, 256, 0, stream>>>(
        zbuf, conv_W1 + (size_t)i * H * H, conv_b1 + (size_t)i * H,
        conv_W2 + (size_t)i * H * H, conv_b2 + (size_t)i * H, out, i, N);
    if (i < L - 1) {
      graph_sum_kernel<<<G, 256, 0, stream>>>(out + (size_t)i * H, vn, vt, N, G);
      vn_mlp_kernel<<<G, 128, 0, stream>>>(vt, vn_W1 + (size_t)i * H * H,
                                           vn_b1 + (size_t)i * H,
                                           vn_W2 + (size_t)i * H * H,
                                           vn_b2 + (size_t)i * H, vn, G);
    }
  }
}

// Round 3
// 623.325 us; speedup vs baseline: 1.6939x; 1.2428x over previous
//
#include <hip/hip_runtime.h>

// Problem constants (fixed by the reference file)
#define NN 50000
#define EE 800000
#define HH 128
#define LL 4
#define GG 64
#define NR 50048  // NN rounded up to 64 (mlp tile granularity)

typedef short bf16x8 __attribute__((ext_vector_type(8)));
typedef float f32x4 __attribute__((ext_vector_type(4)));

// ---------------------------------------------------------------------------
// bf16 pack helpers (RTNE)
// ---------------------------------------------------------------------------
__device__ __forceinline__ unsigned bf_round(float f) {
  unsigned u = __float_as_uint(f);
  return (u + 0x7fffu + ((u >> 16) & 1u)) >> 16;
}
__device__ __forceinline__ unsigned bf_pack2(float lo, float hi) {
  return bf_round(lo) | (bf_round(hi) << 16);
}

// ---------------------------------------------------------------------------
// CSR build: count in-degree, 3-phase parallel exclusive scan, scatter edges
// sorted by target as int2{src, attr_bits}.
// ---------------------------------------------------------------------------
__global__ __launch_bounds__(256) void count_kernel(const int* __restrict__ tgt,
                                                    int* __restrict__ cnt, int E) {
  int e = blockIdx.x * 256 + threadIdx.x;
  if (e < E) atomicAdd(&cnt[tgt[e]], 1);
}

__global__ __launch_bounds__(256) void blocksum_kernel(const int* __restrict__ cnt,
                                                       int* __restrict__ bs, int N) {
  int i = blockIdx.x * 256 + threadIdx.x;
  int v = (i < N) ? cnt[i] : 0;
  __shared__ int sm[256];
  sm[threadIdx.x] = v;
  __syncthreads();
  for (int s = 128; s >= 1; s >>= 1) {
    if (threadIdx.x < s) sm[threadIdx.x] += sm[threadIdx.x + s];
    __syncthreads();
  }
  if (threadIdx.x == 0) bs[blockIdx.x] = sm[0];
}

__global__ __launch_bounds__(256) void bs_scan_kernel(int* __restrict__ bs, int nb) {
  __shared__ int sm[256];
  int t = threadIdx.x;
  int v = (t < nb) ? bs[t] : 0;
  sm[t] = v;
  __syncthreads();
  for (int off = 1; off < 256; off <<= 1) {
    int u = (t >= off) ? sm[t - off] : 0;
    __syncthreads();
    sm[t] += u;
    __syncthreads();
  }
  if (t < nb) bs[t] = sm[t] - v;
  if (t == 255) bs[nb] = sm[255];
}

__global__ __launch_bounds__(256) void blockscan_kernel(const int* __restrict__ cnt,
                                                        const int* __restrict__ bs,
                                                        int* __restrict__ rp, int N, int nb) {
  int b = blockIdx.x, t = threadIdx.x;
  int i = b * 256 + t;
  int v = (i < N) ? cnt[i] : 0;
  __shared__ int sm[256];
  sm[t] = v;
  __syncthreads();
  for (int off = 1; off < 256; off <<= 1) {
    int u = (t >= off) ? sm[t - off] : 0;
    __syncthreads();
    sm[t] += u;
    __syncthreads();
  }
  if (i < N) rp[i] = sm[t] - v + bs[b];
  if (b == 0 && t == 0) rp[N] = bs[nb];
}

__global__ __launch_bounds__(256) void scatter_kernel(const int* __restrict__ src,
                                                      const int* __restrict__ tgt,
                                                      const float* __restrict__ attr,
                                                      const int* __restrict__ rp,
                                                      int* __restrict__ cur,
                                                      int2* __restrict__ es, int E) {
  int e = blockIdx.x * 256 + threadIdx.x;
  if (e < E) {
    int t = tgt[e];
    int p = rp[t] + atomicAdd(&cur[t], 1);
    int2 rec;
    rec.x = src[e];
    rec.y = __float_as_int(attr[e]);
    es[p] = rec;
  }
}

__global__ __launch_bounds__(256) void vn_init_kernel(const float* __restrict__ emb,
                                                      float* __restrict__ vn, int total) {
  int i = blockIdx.x * 256 + threadIdx.x;
  if (i < total) vn[i] = emb[i & (HH - 1)];
}

// Transpose + bf16-convert the conv MLP weights: Wt[n][k] = bf16(W[k][n]).
// 2*L matrices of 128x128; one thread per output element.
__global__ __launch_bounds__(256) void wtconv_kernel(const float* __restrict__ W1,
                                                     const float* __restrict__ W2,
                                                     short* __restrict__ wt1,
                                                     short* __restrict__ wt2) {
  int idx = blockIdx.x * 256 + threadIdx.x;  // [0, 2*L*16384)
  int m = idx >> 14;
  int r = idx & 16383;
  int n = r >> 7, k = r & 127;
  const float* W = (m < LL) ? (W1 + (size_t)m * 16384) : (W2 + (size_t)(m - LL) * 16384);
  short* D = (m < LL) ? (wt1 + (size_t)m * 16384) : (wt2 + (size_t)(m - LL) * 16384);
  D[n * 128 + k] = (short)bf_round(W[k * 128 + n]);
}

// hbf[n] = bf16(h_prev[n] + vn[batch[n]]), packed 2 cols per uint (row = 256 B)
__global__ __launch_bounds__(256) void pack_kernel(const float4* __restrict__ hp, int pitch4,
                                                   const float4* __restrict__ vn,
                                                   const int* __restrict__ batch,
                                                   uint2* __restrict__ hbf, int N) {
  int idx = blockIdx.x * 256 + threadIdx.x;
  if (idx >= N * (HH / 4)) return;
  int n = idx >> 5;  // HH/4 == 32
  int c4 = idx & 31;
  int g = batch[n];
  float4 a = hp[(size_t)n * pitch4 + c4];
  float4 b = vn[g * 32 + c4];
  uint2 o;
  o.x = bf_pack2(a.x + b.x, a.y + b.y);
  o.y = bf_pack2(a.z + b.z, a.w + b.w);
  hbf[idx] = o;
}

// z[n] = (1+eps)*(h[n]+vn[g]) + (1/deg) * sum_e relu(hbf[src_e] + attr_e*eW + eb)
// One wave per node; lane owns bf16x2 column pair; edge loop unrolled 8x for
// memory-level parallelism. Output written as packed bf16 (row = 256 B) for
// the MFMA MLP.
__global__ __launch_bounds__(128) void agg_kernel(const unsigned* __restrict__ hbf,
                                                  const float2* __restrict__ hp2, int pitch2,
                                                  const float2* __restrict__ vn2,
                                                  const int* __restrict__ batch,
                                                  const int2* __restrict__ es,
                                                  const int* __restrict__ rp,
                                                  const float2* __restrict__ eW2,
                                                  const float2* __restrict__ eb2,
                                                  const float* __restrict__ epsp,
                                                  unsigned* __restrict__ zb, int N) {
  int wave = threadIdx.x >> 6;
  int lane = threadIdx.x & 63;
  int n = blockIdx.x * 2 + wave;
  if (n >= N) return;
  float2 ew = eW2[lane];
  float2 eb = eb2[lane];
  int rs = rp[n], re = rp[n + 1];
  float acc0 = 0.f, acc1 = 0.f;
  int k = rs;
  for (; k + 8 <= re; k += 8) {
    int2 e[8];
    unsigned p[8];
#pragma unroll
    for (int u = 0; u < 8; ++u) e[u] = es[k + u];
#pragma unroll
    for (int u = 0; u < 8; ++u) p[u] = hbf[((unsigned)e[u].x << 6) + lane];
#pragma unroll
    for (int u = 0; u < 8; ++u) {
      float a = __int_as_float(e[u].y);
      acc0 += fmaxf(__uint_as_float(p[u] << 16) + fmaf(a, ew.x, eb.x), 0.f);
      acc1 += fmaxf(__uint_as_float(p[u] & 0xffff0000u) + fmaf(a, ew.y, eb.y), 0.f);
    }
  }
  for (; k + 4 <= re; k += 4) {
    int2 e[4];
    unsigned p[4];
#pragma unroll
    for (int u = 0; u < 4; ++u) e[u] = es[k + u];
#pragma unroll
    for (int u = 0; u < 4; ++u) p[u] = hbf[((unsigned)e[u].x << 6) + lane];
#pragma unroll
    for (int u = 0; u < 4; ++u) {
      float a = __int_as_float(e[u].y);
      acc0 += fmaxf(__uint_as_float(p[u] << 16) + fmaf(a, ew.x, eb.x), 0.f);
      acc1 += fmaxf(__uint_as_float(p[u] & 0xffff0000u) + fmaf(a, ew.y, eb.y), 0.f);
    }
  }
  for (; k < re; ++k) {
    int2 e = es[k];
    unsigned p = hbf[((unsigned)e.x << 6) + lane];
    float a = __int_as_float(e.y);
    acc0 += fmaxf(__uint_as_float(p << 16) + fmaf(a, ew.x, eb.x), 0.f);
    acc1 += fmaxf(__uint_as_float(p & 0xffff0000u) + fmaf(a, ew.y, eb.y), 0.f);
  }
  int g = batch[n];
  float2 h = hp2[(size_t)n * pitch2 + lane];
  float2 v = vn2[(size_t)g * 64 + lane];
  float hs0 = h.x + v.x;
  float hs1 = h.y + v.y;
  float inv = 1.f / fmaxf((float)(re - rs), 1.f);
  float onep = 1.f + epsp[0];
  float o0 = fmaf(onep, hs0, acc0 * inv);
  float o1 = fmaf(onep, hs1, acc1 * inv);
  zb[(size_t)n * 64 + lane] = bf_pack2(o0, o1);
}

// h_new = relu(z @ W1 + b1) @ W2 + b2 -> out[:, layer*128:+128], via bf16 MFMA.
// Block = 64 rows, 4 waves; wave w owns rows [w*16, w*16+16) x all 128 cols
// (1 m-tile x 8 n-tiles of 16x16x32 MFMA, K = 4 steps of 32). Each wave stages
// and reads only its own rows -> NO barriers. A from LDS (pitch 272 B: 2-way
// bank aliasing max = free); B from global bf16 Wt[n][k] (L1-resident 32 KB).
__global__ __launch_bounds__(256) void mlp_kernel(const unsigned* __restrict__ zb,
                                                  const short* __restrict__ wt1,
                                                  const float* __restrict__ b1,
                                                  const short* __restrict__ wt2,
                                                  const float* __restrict__ b2,
                                                  float* __restrict__ out, int layer, int N) {
  __shared__ char smem[64 * 272];
  int tid = threadIdx.x;
  int w = tid >> 6, lane = tid & 63;
  int l15 = lane & 15, q = lane >> 4;
  int row0 = blockIdx.x * 64;
  int wrow = w * 16;

  // stage this wave's 16 rows (bf16, 256 B each) into LDS
  const uint4* z4 = (const uint4*)zb;
#pragma unroll
  for (int it = 0; it < 4; ++it) {
    int f = lane + it * 64;
    int r = f >> 4, c16 = f & 15;
    uint4 v = z4[(size_t)(row0 + wrow + r) * 16 + c16];
    *(uint4*)(&smem[(wrow + r) * 272 + c16 * 16]) = v;
  }

  f32x4 zero = {0.f, 0.f, 0.f, 0.f};
  f32x4 acc[8];
#pragma unroll
  for (int j = 0; j < 8; ++j) acc[j] = zero;

  // GEMM1: inter = z @ W1
#pragma unroll
  for (int s = 0; s < 4; ++s) {
    bf16x8 af = *(const bf16x8*)(&smem[(wrow + l15) * 272 + (s * 32 + q * 8) * 2]);
#pragma unroll
    for (int j = 0; j < 8; ++j) {
      bf16x8 bf = *(const bf16x8*)(wt1 + (size_t)(j * 16 + l15) * 128 + s * 32 + q * 8);
      acc[j] = __builtin_amdgcn_mfma_f32_16x16x32_bf16(af, bf, acc[j], 0, 0, 0);
    }
  }
  // epilogue1: +b1, relu, bf16 -> back into same LDS rows (own rows only)
#pragma unroll
  for (int j = 0; j < 8; ++j) {
    float bv = b1[j * 16 + l15];
#pragma unroll
    for (int r = 0; r < 4; ++r) {
      float v = fmaxf(acc[j][r] + bv, 0.f);
      *(short*)(&smem[(wrow + q * 4 + r) * 272 + (j * 16 + l15) * 2]) = (short)bf_round(v);
    }
    acc[j] = zero;
  }
  // GEMM2: h = inter @ W2
#pragma unroll
  for (int s = 0; s < 4; ++s) {
    bf16x8 af = *(const bf16x8*)(&smem[(wrow + l15) * 272 + (s * 32 + q * 8) * 2]);
#pragma unroll
    for (int j = 0; j < 8; ++j) {
      bf16x8 bf = *(const bf16x8*)(wt2 + (size_t)(j * 16 + l15) * 128 + s * 32 + q * 8);
      acc[j] = __builtin_amdgcn_mfma_f32_16x16x32_bf16(af, bf, acc[j], 0, 0, 0);
    }
  }
  // epilogue2: +b2, store fp32 to out slice
#pragma unroll
  for (int j = 0; j < 8; ++j) {
    float bv = b2[j * 16 + l15];
#pragma unroll
    for (int r = 0; r < 4; ++r) {
      int row = row0 + wrow + q * 4 + r;
      if (row < N)
        out[(size_t)row * (LL * HH) + layer * HH + j * 16 + l15] = acc[j][r] + bv;
    }
  }
}

// partial per-(graph, chunk) sums of the layer's out slice: 512 blocks
__global__ __launch_bounds__(256) void gs_partial_kernel(const float* __restrict__ outbase,
                                                         float* __restrict__ part,
                                                         int N, int G) {
  int g = blockIdx.x >> 3, c = blockIdx.x & 7;
  int start = (int)(((long long)g * N + G - 1) / G);
  int end = (int)(((long long)(g + 1) * N + G - 1) / G);
  int len = end - start;
  int cs = start + (len * c) / 8;
  int ce = start + (len * (c + 1)) / 8;
  int c4 = threadIdx.x & 31;
  int rl = threadIdx.x >> 5;
  const float4* ob = (const float4*)outbase;  // pitch = LL*HH/4
  float4 acc = make_float4(0.f, 0.f, 0.f, 0.f);
  for (int n = cs + rl; n < ce; n += 8) {
    float4 v = ob[(size_t)n * (LL * HH / 4) + c4];
    acc.x += v.x; acc.y += v.y; acc.z += v.z; acc.w += v.w;
  }
  __shared__ float4 sm[256];
  sm[threadIdx.x] = acc;
  __syncthreads();
  for (int s = 4; s >= 1; s >>= 1) {
    if (rl < s) {
      float4 o = sm[(rl + s) * 32 + c4];
      float4 m = sm[rl * 32 + c4];
      m.x += o.x; m.y += o.y; m.z += o.z; m.w += o.w;
      sm[rl * 32 + c4] = m;
    }
    __syncthreads();
  }
  if (rl == 0) ((float4*)part)[(size_t)blockIdx.x * 32 + c4] = sm[c4];
}

// vn = relu(relu((sum_c part + vn) @ W1 + b1) @ W2 + b2) — one block/graph
__global__ __launch_bounds__(128) void vn_fused_kernel(const float* __restrict__ part,
                                                       const float* __restrict__ W1,
                                                       const float* __restrict__ b1,
                                                       const float* __restrict__ W2,
                                                       const float* __restrict__ b2,
                                                       float* __restrict__ vn, int G) {
  int g = blockIdx.x, j = threadIdx.x;
  __shared__ float vr[128];
  __shared__ float tr[128];
  float s = vn[g * HH + j];
#pragma unroll
  for (int c = 0; c < 8; ++c) s += part[(size_t)(g * 8 + c) * HH + j];
  vr[j] = s;
  __syncthreads();
  float a = b1[j];
  for (int k = 0; k < 128; ++k) a = fmaf(vr[k], W1[k * HH + j], a);
  tr[j] = fmaxf(a, 0.f);
  __syncthreads();
  float o = b2[j];
  for (int k = 0; k < 128; ++k) o = fmaf(tr[k], W2[k * HH + j], o);
  vn[g * HH + j] = fmaxf(o, 0.f);
}

extern "C" void kernel_launch(void* const* d_in, const int* in_sizes, int n_in,
                              void* d_out, int out_size, void* d_ws, size_t ws_size,
                              hipStream_t stream) {
  const int N = NN, E = EE, H = HH, L = LL, G = GG;
  const float* x          = (const float*)d_in[0];
  const float* edge_attr  = (const float*)d_in[1];
  const float* conv_W1    = (const float*)d_in[2];
  const float* conv_b1    = (const float*)d_in[3];
  const float* conv_W2    = (const float*)d_in[4];
  const float* conv_b2    = (const float*)d_in[5];
  const float* conv_eps   = (const float*)d_in[6];
  const float* edge_W     = (const float*)d_in[7];
  const float* edge_b     = (const float*)d_in[8];
  const float* vn_W1      = (const float*)d_in[9];
  const float* vn_b1      = (const float*)d_in[10];
  const float* vn_W2      = (const float*)d_in[11];
  const float* vn_b2      = (const float*)d_in[12];
  const float* vn_emb     = (const float*)d_in[13];
  const int*   edge_index = (const int*)d_in[14];
  const int*   batch      = (const int*)d_in[15];
  float* out = (float*)d_out;

  const int nb = (N + 255) / 256;

  // workspace carve-up (~33 MB)
  char* ws = (char*)d_ws;
  size_t off = 0;
  auto take = [&](size_t bytes) -> void* {
    void* p = ws + off;
    off = (off + bytes + 255) & ~(size_t)255;
    return p;
  };
  int*      cnt  = (int*)take((size_t)N * 4);
  int*      rp   = (int*)take((size_t)(N + 1) * 4);
  int*      bs   = (int*)take((size_t)(nb + 1) * 4);
  int2*     es   = (int2*)take((size_t)E * 8);
  unsigned* hbf  = (unsigned*)take((size_t)N * (H / 2) * 4);   // bf16 h+vn
  unsigned* zb   = (unsigned*)take((size_t)NR * (H / 2) * 4);  // bf16 z
  short*    wt1  = (short*)take((size_t)L * H * H * 2);        // bf16 W1^T
  short*    wt2  = (short*)take((size_t)L * H * H * 2);        // bf16 W2^T
  float*    part = (float*)take((size_t)G * 8 * H * 4);
  float*    vn   = (float*)take((size_t)G * H * 4);

  const int* src = edge_index;
  const int* tgt = edge_index + E;

  // CSR build
  hipMemsetAsync(cnt, 0, (size_t)N * 4, stream);
  count_kernel<<<(E + 255) / 256, 256, 0, stream>>>(tgt, cnt, E);
  blocksum_kernel<<<nb, 256, 0, stream>>>(cnt, bs, N);
  bs_scan_kernel<<<1, 256, 0, stream>>>(bs, nb);
  blockscan_kernel<<<nb, 256, 0, stream>>>(cnt, bs, rp, N, nb);
  hipMemsetAsync(cnt, 0, (size_t)N * 4, stream);
  scatter_kernel<<<(E + 255) / 256, 256, 0, stream>>>(src, tgt, edge_attr, rp, cnt, es, E);
  wtconv_kernel<<<(2 * L * H * H) / 256, 256, 0, stream>>>(conv_W1, conv_W2, wt1, wt2);
  vn_init_kernel<<<(G * H + 255) / 256, 256, 0, stream>>>(vn_emb, vn, G * H);

  for (int i = 0; i < L; ++i) {
    const float* hp;
    int pitch;
    if (i == 0) { hp = x; pitch = H; }
    else        { hp = out + (size_t)(i - 1) * H; pitch = L * H; }
    pack_kernel<<<(N * (H / 4) + 255) / 256, 256, 0, stream>>>(
        (const float4*)hp, pitch / 4, (const float4*)vn, batch, (uint2*)hbf, N);
    agg_kernel<<<(N + 1) / 2, 128, 0, stream>>>(
        hbf, (const float2*)hp, pitch / 2, (const float2*)vn, batch, es, rp,
        (const float2*)(edge_W + (size_t)i * H), (const float2*)(edge_b + (size_t)i * H),
        conv_eps + i, zb, N);
    mlp_kernel<<<NR / 64, 256, 0, stream>>>(
        zb, wt1 + (size_t)i * H * H, conv_b1 + (size_t)i * H,
        wt2 + (size_t)i * H * H, conv_b2 + (size_t)i * H, out, i, N);
    if (i < L - 1) {
      gs_partial_kernel<<<G * 8, 256, 0, stream>>>(out + (size_t)i * H, part, N, G);
      vn_fused_kernel<<<G, 128, 0, stream>>>(part, vn_W1 + (size_t)i * H * H,
                                             vn_b1 + (size_t)i * H,
                                             vn_W2 + (size_t)i * H * H,
                                             vn_b2 + (size_t)i * H, vn, G);
    }
  }
}

// Round 4
// 621.150 us; speedup vs baseline: 1.6998x; 1.0035x over previous
//
#include <hip/hip_runtime.h>

// Problem constants (fixed by the reference file)
#define NN 50000
#define EE 800000
#define HH 128
#define LL 4
#define GG 64
#define NR 50048  // NN rounded up to 64 (mlp tile granularity)

typedef short bf16x8 __attribute__((ext_vector_type(8)));
typedef float f32x4 __attribute__((ext_vector_type(4)));

// ---------------------------------------------------------------------------
// bf16 pack helpers (RTNE)
// ---------------------------------------------------------------------------
__device__ __forceinline__ unsigned bf_round(float f) {
  unsigned u = __float_as_uint(f);
  return (u + 0x7fffu + ((u >> 16) & 1u)) >> 16;
}
__device__ __forceinline__ unsigned bf_pack2(float lo, float hi) {
  return bf_round(lo) | (bf_round(hi) << 16);
}

// ---------------------------------------------------------------------------
// CSR build
// ---------------------------------------------------------------------------
__global__ __launch_bounds__(256) void count_kernel(const int* __restrict__ tgt,
                                                    int* __restrict__ cnt, int E) {
  int e = blockIdx.x * 256 + threadIdx.x;
  if (e < E) atomicAdd(&cnt[tgt[e]], 1);
}

__global__ __launch_bounds__(256) void blocksum_kernel(const int* __restrict__ cnt,
                                                       int* __restrict__ bs, int N) {
  int i = blockIdx.x * 256 + threadIdx.x;
  int v = (i < N) ? cnt[i] : 0;
  __shared__ int sm[256];
  sm[threadIdx.x] = v;
  __syncthreads();
  for (int s = 128; s >= 1; s >>= 1) {
    if (threadIdx.x < s) sm[threadIdx.x] += sm[threadIdx.x + s];
    __syncthreads();
  }
  if (threadIdx.x == 0) bs[blockIdx.x] = sm[0];
}

__global__ __launch_bounds__(256) void bs_scan_kernel(int* __restrict__ bs, int nb) {
  __shared__ int sm[256];
  int t = threadIdx.x;
  int v = (t < nb) ? bs[t] : 0;
  sm[t] = v;
  __syncthreads();
  for (int off = 1; off < 256; off <<= 1) {
    int u = (t >= off) ? sm[t - off] : 0;
    __syncthreads();
    sm[t] += u;
    __syncthreads();
  }
  if (t < nb) bs[t] = sm[t] - v;
  if (t == 255) bs[nb] = sm[255];
}

// also zeroes the scatter cursor (saves one memset dispatch)
__global__ __launch_bounds__(256) void blockscan_kernel(const int* __restrict__ cnt,
                                                        const int* __restrict__ bs,
                                                        int* __restrict__ rp,
                                                        int* __restrict__ cur, int N, int nb) {
  int b = blockIdx.x, t = threadIdx.x;
  int i = b * 256 + t;
  int v = (i < N) ? cnt[i] : 0;
  __shared__ int sm[256];
  sm[t] = v;
  __syncthreads();
  for (int off = 1; off < 256; off <<= 1) {
    int u = (t >= off) ? sm[t - off] : 0;
    __syncthreads();
    sm[t] += u;
    __syncthreads();
  }
  if (i < N) { rp[i] = sm[t] - v + bs[b]; cur[i] = 0; }
  if (b == 0 && t == 0) rp[N] = bs[nb];
}

__global__ __launch_bounds__(256) void scatter_kernel(const int* __restrict__ src,
                                                      const int* __restrict__ tgt,
                                                      const float* __restrict__ attr,
                                                      const int* __restrict__ rp,
                                                      int* __restrict__ cur,
                                                      int2* __restrict__ es, int E) {
  int e = blockIdx.x * 256 + threadIdx.x;
  if (e < E) {
    int t = tgt[e];
    int p = rp[t] + atomicAdd(&cur[t], 1);
    int2 rec;
    rec.x = src[e];
    rec.y = __float_as_int(attr[e]);
    es[p] = rec;
  }
}

// Fused one-time init: weight transpose+bf16 (2*L*128*128), vn init (G*H),
// part zero (G*H).
__global__ __launch_bounds__(256) void init_kernel(const float* __restrict__ W1,
                                                   const float* __restrict__ W2,
                                                   const float* __restrict__ emb,
                                                   short* __restrict__ wt1,
                                                   short* __restrict__ wt2,
                                                   float* __restrict__ vn,
                                                   float* __restrict__ part) {
  int idx = blockIdx.x * 256 + threadIdx.x;
  const int NW = 2 * LL * HH * HH;  // 131072
  if (idx < NW) {
    int m = idx >> 14;
    int r = idx & 16383;
    int n = r >> 7, k = r & 127;
    const float* W = (m < LL) ? (W1 + (size_t)m * 16384) : (W2 + (size_t)(m - LL) * 16384);
    short* D = (m < LL) ? (wt1 + (size_t)m * 16384) : (wt2 + (size_t)(m - LL) * 16384);
    D[n * 128 + k] = (short)bf_round(W[k * 128 + n]);
  } else if (idx < NW + GG * HH) {
    int i = idx - NW;
    vn[i] = emb[i & (HH - 1)];
  } else if (idx < NW + 2 * GG * HH) {
    part[idx - NW - GG * HH] = 0.f;
  }
}

// hbf[n] = bf16(h_prev[n] + vn[batch[n]]), packed 2 cols per uint (row = 256 B)
__global__ __launch_bounds__(256) void pack_kernel(const float4* __restrict__ hp, int pitch4,
                                                   const float4* __restrict__ vn,
                                                   const int* __restrict__ batch,
                                                   uint2* __restrict__ hbf, int N) {
  int idx = blockIdx.x * 256 + threadIdx.x;
  if (idx >= N * (HH / 4)) return;
  int n = idx >> 5;  // HH/4 == 32
  int c4 = idx & 31;
  int g = batch[n];
  float4 a = hp[(size_t)n * pitch4 + c4];
  float4 b = vn[g * 32 + c4];
  uint2 o;
  o.x = bf_pack2(a.x + b.x, a.y + b.y);
  o.y = bf_pack2(a.z + b.z, a.w + b.w);
  hbf[idx] = o;
}

__device__ __forceinline__ void accum8(float* acc, uint4 p, float a,
                                       const float4& ew0, const float4& ew1,
                                       const float4& eb0, const float4& eb1, float m) {
  float lo, hi;
  lo = __uint_as_float(p.x << 16); hi = __uint_as_float(p.x & 0xffff0000u);
  acc[0] += m * fmaxf(lo + fmaf(a, ew0.x, eb0.x), 0.f);
  acc[1] += m * fmaxf(hi + fmaf(a, ew0.y, eb0.y), 0.f);
  lo = __uint_as_float(p.y << 16); hi = __uint_as_float(p.y & 0xffff0000u);
  acc[2] += m * fmaxf(lo + fmaf(a, ew0.z, eb0.z), 0.f);
  acc[3] += m * fmaxf(hi + fmaf(a, ew0.w, eb0.w), 0.f);
  lo = __uint_as_float(p.z << 16); hi = __uint_as_float(p.z & 0xffff0000u);
  acc[4] += m * fmaxf(lo + fmaf(a, ew1.x, eb1.x), 0.f);
  acc[5] += m * fmaxf(hi + fmaf(a, ew1.y, eb1.y), 0.f);
  lo = __uint_as_float(p.w << 16); hi = __uint_as_float(p.w & 0xffff0000u);
  acc[6] += m * fmaxf(lo + fmaf(a, ew1.z, eb1.z), 0.f);
  acc[7] += m * fmaxf(hi + fmaf(a, ew1.w, eb1.w), 0.f);
}

// z[n] = (1+eps)*(h[n]+vn[g]) + (1/deg) * sum_e relu(hbf[src_e] + attr_e*eW + eb)
// One wave per node. Lane = (quad q, col-group c): lane loads uint4 (16 B =
// 8 bf16 cols) of edge k+q -> one VMEM instruction covers 4 edges / 16 cache
// lines; main loop keeps 2 such loads (8 edges, 32 lines) in flight. Per-node
// cross-quad combine via 2 shuffle-xor rounds. Output packed bf16 row (256 B).
__global__ __launch_bounds__(128) void agg_kernel(const uint4* __restrict__ hbf4,
                                                  const float* __restrict__ hp, int pitch,
                                                  const float* __restrict__ vnp,
                                                  const int* __restrict__ batch,
                                                  const int2* __restrict__ es,
                                                  const int* __restrict__ rp,
                                                  const float* __restrict__ eW,
                                                  const float* __restrict__ eb,
                                                  const float* __restrict__ epsp,
                                                  uint4* __restrict__ zb4, int N) {
  int wave = threadIdx.x >> 6;
  int lane = threadIdx.x & 63;
  int n = blockIdx.x * 2 + wave;
  if (n >= N) return;
  int q = lane >> 4;
  int c = lane & 15;  // cols [c*8, c*8+8)
  float4 ew0 = *(const float4*)(eW + c * 8);
  float4 ew1 = *(const float4*)(eW + c * 8 + 4);
  float4 eb0 = *(const float4*)(eb + c * 8);
  float4 eb1 = *(const float4*)(eb + c * 8 + 4);
  int rs = rp[n], re = rp[n + 1];
  float acc[8];
#pragma unroll
  for (int j = 0; j < 8; ++j) acc[j] = 0.f;
  int k = rs;
  for (; k + 8 <= re; k += 8) {
    int2 e0 = es[k + q];
    int2 e1 = es[k + 4 + q];
    uint4 p0 = hbf4[(size_t)e0.x * 16 + c];
    uint4 p1 = hbf4[(size_t)e1.x * 16 + c];
    accum8(acc, p0, __int_as_float(e0.y), ew0, ew1, eb0, eb1, 1.f);
    accum8(acc, p1, __int_as_float(e1.y), ew0, ew1, eb0, eb1, 1.f);
  }
  for (; k < re; k += 4) {
    int idx = min(k + q, re - 1);
    int2 e = es[idx];
    float m = (k + q < re) ? 1.f : 0.f;
    uint4 p = hbf4[(size_t)e.x * 16 + c];
    accum8(acc, p, __int_as_float(e.y), ew0, ew1, eb0, eb1, m);
  }
  // cross-quad reduce: lanes with same c across quads hold partials
#pragma unroll
  for (int j = 0; j < 8; ++j) {
    acc[j] += __shfl_xor(acc[j], 16);
    acc[j] += __shfl_xor(acc[j], 32);
  }
  int g = batch[n];
  const float* hrow = hp + (size_t)n * pitch + c * 8;
  const float* vrow = vnp + g * HH + c * 8;
  float4 h0 = *(const float4*)(hrow);
  float4 h1 = *(const float4*)(hrow + 4);
  float4 v0 = *(const float4*)(vrow);
  float4 v1 = *(const float4*)(vrow + 4);
  float inv = 1.f / fmaxf((float)(re - rs), 1.f);
  float onep = 1.f + epsp[0];
  uint4 o;
  o.x = bf_pack2(fmaf(onep, h0.x + v0.x, acc[0] * inv),
                 fmaf(onep, h0.y + v0.y, acc[1] * inv));
  o.y = bf_pack2(fmaf(onep, h0.z + v0.z, acc[2] * inv),
                 fmaf(onep, h0.w + v0.w, acc[3] * inv));
  o.z = bf_pack2(fmaf(onep, h1.x + v1.x, acc[4] * inv),
                 fmaf(onep, h1.y + v1.y, acc[5] * inv));
  o.w = bf_pack2(fmaf(onep, h1.z + v1.z, acc[6] * inv),
                 fmaf(onep, h1.w + v1.w, acc[7] * inv));
  if (q == 0) zb4[(size_t)n * 16 + c] = o;
}

// h_new = relu(z @ W1 + b1) @ W2 + b2 -> out[:, layer*128:+128], via bf16 MFMA.
// Block = 64 rows, 4 waves; wave w owns rows [w*16, w*16+16); no barriers.
// Epilogue additionally accumulates the per-graph column sums (jumping-knowledge
// virtual-node input) via shuffle-reduce + atomicAdd into part[] when do_gs.
__global__ __launch_bounds__(256) void mlp_kernel(const unsigned* __restrict__ zb,
                                                  const short* __restrict__ wt1,
                                                  const float* __restrict__ b1,
                                                  const short* __restrict__ wt2,
                                                  const float* __restrict__ b2,
                                                  float* __restrict__ out,
                                                  float* __restrict__ part,
                                                  int do_gs, int layer, int N) {
  __shared__ char smem[64 * 272];
  int tid = threadIdx.x;
  int w = tid >> 6, lane = tid & 63;
  int l15 = lane & 15, q = lane >> 4;
  int row0 = blockIdx.x * 64;
  int wrow = w * 16;

  const uint4* z4 = (const uint4*)zb;
#pragma unroll
  for (int it = 0; it < 4; ++it) {
    int f = lane + it * 64;
    int r = f >> 4, c16 = f & 15;
    uint4 v = z4[(size_t)(row0 + wrow + r) * 16 + c16];
    *(uint4*)(&smem[(wrow + r) * 272 + c16 * 16]) = v;
  }

  f32x4 zero = {0.f, 0.f, 0.f, 0.f};
  f32x4 acc[8];
#pragma unroll
  for (int j = 0; j < 8; ++j) acc[j] = zero;

#pragma unroll
  for (int s = 0; s < 4; ++s) {
    bf16x8 af = *(const bf16x8*)(&smem[(wrow + l15) * 272 + (s * 32 + q * 8) * 2]);
#pragma unroll
    for (int j = 0; j < 8; ++j) {
      bf16x8 bf = *(const bf16x8*)(wt1 + (size_t)(j * 16 + l15) * 128 + s * 32 + q * 8);
      acc[j] = __builtin_amdgcn_mfma_f32_16x16x32_bf16(af, bf, acc[j], 0, 0, 0);
    }
  }
#pragma unroll
  for (int j = 0; j < 8; ++j) {
    float bv = b1[j * 16 + l15];
#pragma unroll
    for (int r = 0; r < 4; ++r) {
      float v = fmaxf(acc[j][r] + bv, 0.f);
      *(short*)(&smem[(wrow + q * 4 + r) * 272 + (j * 16 + l15) * 2]) = (short)bf_round(v);
    }
    acc[j] = zero;
  }
#pragma unroll
  for (int s = 0; s < 4; ++s) {
    bf16x8 af = *(const bf16x8*)(&smem[(wrow + l15) * 272 + (s * 32 + q * 8) * 2]);
#pragma unroll
    for (int j = 0; j < 8; ++j) {
      bf16x8 bf = *(const bf16x8*)(wt2 + (size_t)(j * 16 + l15) * 128 + s * 32 + q * 8);
      acc[j] = __builtin_amdgcn_mfma_f32_16x16x32_bf16(af, bf, acc[j], 0, 0, 0);
    }
  }
  int g0 = (int)(((long long)row0 * GG) / NN);
#pragma unroll
  for (int j = 0; j < 8; ++j) {
    float bv = b2[j * 16 + l15];
    float s0 = 0.f, s1 = 0.f;
#pragma unroll
    for (int r = 0; r < 4; ++r) {
      int row = row0 + wrow + q * 4 + r;
      if (row < N) {
        float v = acc[j][r] + bv;
        out[(size_t)row * (LL * HH) + layer * HH + j * 16 + l15] = v;
        if (do_gs) {
          int rel = (int)(((long long)row * GG) / NN) - g0;
          if (rel == 0) s0 += v; else s1 += v;
        }
      }
    }
    if (do_gs) {
      s0 += __shfl_xor(s0, 16); s0 += __shfl_xor(s0, 32);
      s1 += __shfl_xor(s1, 16); s1 += __shfl_xor(s1, 32);
      if (q == 0) {
        atomicAdd(&part[g0 * HH + j * 16 + l15], s0);
        if (s1 != 0.f) atomicAdd(&part[(g0 + 1) * HH + j * 16 + l15], s1);
      }
    }
  }
}

// vn = relu(relu((part + vn) @ W1 + b1) @ W2 + b2); re-zeroes part for the
// next layer's atomics. One block per graph.
__global__ __launch_bounds__(128) void vn_fused_kernel(float* __restrict__ part,
                                                       const float* __restrict__ W1,
                                                       const float* __restrict__ b1,
                                                       const float* __restrict__ W2,
                                                       const float* __restrict__ b2,
                                                       float* __restrict__ vn, int G) {
  int g = blockIdx.x, j = threadIdx.x;
  __shared__ float vr[128];
  __shared__ float tr[128];
  vr[j] = vn[g * HH + j] + part[g * HH + j];
  part[g * HH + j] = 0.f;
  __syncthreads();
  float a = b1[j];
  for (int k = 0; k < 128; ++k) a = fmaf(vr[k], W1[k * HH + j], a);
  tr[j] = fmaxf(a, 0.f);
  __syncthreads();
  float o = b2[j];
  for (int k = 0; k < 128; ++k) o = fmaf(tr[k], W2[k * HH + j], o);
  vn[g * HH + j] = fmaxf(o, 0.f);
}

extern "C" void kernel_launch(void* const* d_in, const int* in_sizes, int n_in,
                              void* d_out, int out_size, void* d_ws, size_t ws_size,
                              hipStream_t stream) {
  const int N = NN, E = EE, H = HH, L = LL, G = GG;
  const float* x          = (const float*)d_in[0];
  const float* edge_attr  = (const float*)d_in[1];
  const float* conv_W1    = (const float*)d_in[2];
  const float* conv_b1    = (const float*)d_in[3];
  const float* conv_W2    = (const float*)d_in[4];
  const float* conv_b2    = (const float*)d_in[5];
  const float* conv_eps   = (const float*)d_in[6];
  const float* edge_W     = (const float*)d_in[7];
  const float* edge_b     = (const float*)d_in[8];
  const float* vn_W1      = (const float*)d_in[9];
  const float* vn_b1      = (const float*)d_in[10];
  const float* vn_W2      = (const float*)d_in[11];
  const float* vn_b2      = (const float*)d_in[12];
  const float* vn_emb     = (const float*)d_in[13];
  const int*   edge_index = (const int*)d_in[14];
  const int*   batch      = (const int*)d_in[15];
  float* out = (float*)d_out;

  const int nb = (N + 255) / 256;

  // workspace carve-up
  char* ws = (char*)d_ws;
  size_t off = 0;
  auto take = [&](size_t bytes) -> void* {
    void* p = ws + off;
    off = (off + bytes + 255) & ~(size_t)255;
    return p;
  };
  int*      cnt  = (int*)take((size_t)N * 4);
  int*      cur  = (int*)take((size_t)N * 4);
  int*      rp   = (int*)take((size_t)(N + 1) * 4);
  int*      bs   = (int*)take((size_t)(nb + 1) * 4);
  int2*     es   = (int2*)take((size_t)E * 8);
  unsigned* hbf  = (unsigned*)take((size_t)N * (H / 2) * 4);   // bf16 h+vn
  unsigned* zb   = (unsigned*)take((size_t)NR * (H / 2) * 4);  // bf16 z
  short*    wt1  = (short*)take((size_t)L * H * H * 2);        // bf16 W1^T
  short*    wt2  = (short*)take((size_t)L * H * H * 2);        // bf16 W2^T
  float*    part = (float*)take((size_t)G * H * 4);
  float*    vn   = (float*)take((size_t)G * H * 4);

  const int* src = edge_index;
  const int* tgt = edge_index + E;

  // CSR build
  hipMemsetAsync(cnt, 0, (size_t)N * 4, stream);
  count_kernel<<<(E + 255) / 256, 256, 0, stream>>>(tgt, cnt, E);
  blocksum_kernel<<<nb, 256, 0, stream>>>(cnt, bs, N);
  bs_scan_kernel<<<1, 256, 0, stream>>>(bs, nb);
  blockscan_kernel<<<nb, 256, 0, stream>>>(cnt, bs, rp, cur, N, nb);
  scatter_kernel<<<(E + 255) / 256, 256, 0, stream>>>(src, tgt, edge_attr, rp, cur, es, E);
  init_kernel<<<(2 * L * H * H + 2 * G * H + 255) / 256, 256, 0, stream>>>(
      conv_W1, conv_W2, vn_emb, wt1, wt2, vn, part);

  for (int i = 0; i < L; ++i) {
    const float* hp;
    int pitch;
    if (i == 0) { hp = x; pitch = H; }
    else        { hp = out + (size_t)(i - 1) * H; pitch = L * H; }
    pack_kernel<<<(N * (H / 4) + 255) / 256, 256, 0, stream>>>(
        (const float4*)hp, pitch / 4, (const float4*)vn, batch, (uint2*)hbf, N);
    agg_kernel<<<(N + 1) / 2, 128, 0, stream>>>(
        (const uint4*)hbf, hp, pitch, vn, batch, es, rp,
        edge_W + (size_t)i * H, edge_b + (size_t)i * H,
        conv_eps + i, (uint4*)zb, N);
    mlp_kernel<<<NR / 64, 256, 0, stream>>>(
        zb, wt1 + (size_t)i * H * H, conv_b1 + (size_t)i * H,
        wt2 + (size_t)i * H * H, conv_b2 + (size_t)i * H, out, part,
        (i < L - 1) ? 1 : 0, i, N);
    if (i < L - 1) {
      vn_fused_kernel<<<G, 128, 0, stream>>>(part, vn_W1 + (size_t)i * H * H,
                                             vn_b1 + (size_t)i * H,
                                             vn_W2 + (size_t)i * H * H,
                                             vn_b2 + (size_t)i * H, vn, G);
    }
  }
}